// Round 2
// baseline (1137.607 us; speedup 1.0000x reference)
//
#include <hip/hip_runtime.h>

#define B_      64
#define CIN     64
#define HW      3136
#define W56     56
#define COUT    128
#define CH512   512
#define IN_DIM  200704
#define SPLIT   392          // split-K blocks; 200704/392 = 512
#define KPER    512
#define CHUNKS  16           // KPER/32
#define XS_STRIDE 72         // padded cin stride for conv x tile
#define WS_STRIDE 40         // padded k stride for conv w tiles
// DIAGNOSTIC (kept one more round; round-1 bench failed before producing data):
// run every kernel body twice (idempotent). dur_us ~2x true total; any kernel with
// true cost >= ~127us becomes visible in rocprof top-5 above the harness ~250us
// fill dispatches, WITH its own counters. Set back to 1 next round.
#define REP 2

#define GPTR(p) ((__attribute__((address_space(1))) void*)(p))
#define SPTR(p) ((__attribute__((address_space(3))) void*)(p))

typedef __attribute__((ext_vector_type(8))) short short8;
typedef __attribute__((ext_vector_type(4))) float floatx4;

union S8U { short8 s; unsigned u[4]; };

__device__ __forceinline__ unsigned short f2bf(float f) {
  unsigned int u = __float_as_uint(f);
  u += 0x7FFFu + ((u >> 16) & 1u);
  return (unsigned short)(u >> 16);
}

// Split 8 fp32 (bit patterns in fa,fb; k-order f0..f7) into hi/lo bf16 short8.
// Bit-identical to v1's split8: hi = RNE(f), lo = RNE(f - bf2f(hi)).
__device__ __forceinline__ void cvt8(uint4 fa, uint4 fb, short8& H, short8& L) {
  unsigned ua[8] = {fa.x, fa.y, fa.z, fa.w, fb.x, fb.y, fb.z, fb.w};
  S8U h, l;
#pragma unroll
  for (int i = 0; i < 4; ++i) {
    unsigned u0 = ua[2 * i], u1 = ua[2 * i + 1];
    unsigned r0 = u0 + 0x7FFFu + ((u0 >> 16) & 1u);
    unsigned r1 = u1 + 0x7FFFu + ((u1 >> 16) & 1u);
    float l0 = __uint_as_float(u0) - __uint_as_float(r0 & 0xFFFF0000u);
    float l1 = __uint_as_float(u1) - __uint_as_float(r1 & 0xFFFF0000u);
    unsigned v0 = __float_as_uint(l0), v1 = __float_as_uint(l1);
    unsigned q0 = v0 + 0x7FFFu + ((v0 >> 16) & 1u);
    unsigned q1 = v1 + 0x7FFFu + ((v1 >> 16) & 1u);
    h.u[i] = (r0 >> 16) | (r1 & 0xFFFF0000u);
    l.u[i] = (q0 >> 16) | (q1 & 0xFFFF0000u);
  }
  H = h.s; L = l.s;
}

// ---------------- K1: x NCHW fp32 -> NHWC bf16 (x_t[b][pos][cin]) -------------
__global__ __launch_bounds__(256) void k_transpose(const float* __restrict__ x,
                                                   unsigned short* __restrict__ xt) {
  __shared__ float tile[64 * 65];
  int bb = blockIdx.x / 49, pt = blockIdx.x % 49;
  int p0 = pt * 64, t = threadIdx.x;
#pragma unroll 1
  for (int rep = 0; rep < REP; ++rep) {
    const float* src = x + ((size_t)bb * 64) * HW + p0;
#pragma unroll
    for (int i = 0; i < 16; ++i) {
      int e = i * 256 + t, ci = e >> 6, ps = e & 63;
      tile[ci * 65 + ps] = src[(size_t)ci * HW + ps];
    }
    __syncthreads();
    unsigned short* dst = xt + ((size_t)bb * HW + p0) * 64;
#pragma unroll
    for (int i = 0; i < 16; ++i) {
      int e = i * 256 + t, ps = e >> 6, ci = e & 63;
      dst[(size_t)ps * 64 + ci] = f2bf(tile[ci * 65 + ps]);
    }
    __syncthreads();
  }
}

// ---------------- K2: router GEMM ---------------------------------------------
// w staged fp32 via global_load_lds double-buffer (exactly 64 KB LDS), hi/lo bf16
// split done on the READ side (bit-identical values to v1's staging-side split).
// x A-fragments read directly from global (1 KB/block/chunk, L2-hot; 4x wave
// redundancy is trivial). LDS slots XOR-swizzled by (row&7); inverse swizzle is
// applied on the per-lane GLOBAL address (both-sides-or-neither rule), so the
// linear wave-uniform DMA destination still lands data where reads expect it.
// partial[s][b(64)][c(512)] fp32 is bit-identical to v1.
__global__ __launch_bounds__(256) void k_router(const float* __restrict__ x,
                                                const float* __restrict__ rw,
                                                float* __restrict__ partial) {
  __shared__ uint4 wbuf[2][2048];  // 2 x 32 KB: [256 rows][32 f32 = 8 slots]
  int nt = blockIdx.x / SPLIT;
  int s = blockIdx.x % SPLIT;
  int kb = s * KPER;
  int t = threadIdx.x, lane = t & 63, wv = t >> 6;
  int l15 = lane & 15, quad = lane >> 4;
  int sub = lane >> 3, cpart = lane & 7;  // 8 lanes per staged row / 16B slot

  const float* wbase = rw + (size_t)(nt * 256) * IN_DIM + kb;
  auto stage = [&](int p, int cc) {
#pragma unroll
    for (int i = 0; i < 8; ++i) {  // wave wv covers rows wv*64 .. wv*64+63
      int row = wv * 64 + i * 8 + sub;
      const float* g = wbase + (size_t)row * IN_DIM + cc * 32 + ((cpart ^ (row & 7)) << 2);
      __builtin_amdgcn_global_load_lds(GPTR(g),
                                       SPTR((char*)&wbuf[p][0] + (wv * 8 + i) * 1024),
                                       16, 0, 0);
    }
  };

#pragma unroll 1
  for (int rep = 0; rep < REP; ++rep) {
    floatx4 acc[4][4];
#pragma unroll
    for (int i = 0; i < 4; ++i)
#pragma unroll
      for (int j = 0; j < 4; ++j) acc[i][j] = (floatx4){0.f, 0.f, 0.f, 0.f};

    stage(0, 0);
    __syncthreads();  // compiler drains vmcnt(0) before s_barrier -> buf0 ready
#pragma unroll 2
    for (int cc = 0; cc < CHUNKS; ++cc) {
      if (cc + 1 < CHUNKS) stage((cc + 1) & 1, cc + 1);  // prefetch hides under compute
      // A fragments straight from global (rows mi*16+l15, k quad*8..quad*8+7)
      short8 Ah[4], Al[4];
#pragma unroll
      for (int mi = 0; mi < 4; ++mi) {
        int r = mi * 16 + l15;
        const uint4* pa = (const uint4*)(x + (size_t)r * IN_DIM + kb + cc * 32 + quad * 8);
        cvt8(pa[0], pa[1], Ah[mi], Al[mi]);
      }
      const uint4* bp = &wbuf[cc & 1][0];
#pragma unroll
      for (int nj = 0; nj < 4; ++nj) {
        int c = wv * 64 + nj * 16 + l15, sw = c & 7;
        uint4 fa = bp[c * 8 + ((quad * 2) ^ sw)];
        uint4 fb = bp[c * 8 + ((quad * 2 + 1) ^ sw)];
        short8 Bh, Bl;
        cvt8(fa, fb, Bh, Bl);
#pragma unroll
        for (int mi = 0; mi < 4; ++mi) {
          acc[mi][nj] = __builtin_amdgcn_mfma_f32_16x16x32_bf16(Ah[mi], Bh, acc[mi][nj], 0, 0, 0);
          acc[mi][nj] = __builtin_amdgcn_mfma_f32_16x16x32_bf16(Al[mi], Bh, acc[mi][nj], 0, 0, 0);
          acc[mi][nj] = __builtin_amdgcn_mfma_f32_16x16x32_bf16(Ah[mi], Bl, acc[mi][nj], 0, 0, 0);
        }
      }
      __syncthreads();
    }
#pragma unroll
    for (int mi = 0; mi < 4; ++mi)
#pragma unroll
      for (int nj = 0; nj < 4; ++nj)
#pragma unroll
        for (int r = 0; r < 4; ++r) {
          int brow = mi * 16 + quad * 4 + r;
          int cg = nt * 256 + wv * 64 + nj * 16 + l15;
          partial[((size_t)s * 64 + brow) * 512 + cg] = acc[mi][nj][r];
        }
  }
}

// ---------------- K3a: reduce partials -> scores[64][512] ---------------------
// Bit-identical to v1's k_topk reduction: one thread per (b,c), sequential s
// order, then +rb. 256 blocks (4x the CU coverage of v1's 64-block version).
__global__ __launch_bounds__(128) void k_reduce(const float* __restrict__ partial,
                                                const float* __restrict__ rb,
                                                float* __restrict__ scores) {
  int b = blockIdx.x >> 2, qq = blockIdx.x & 3;
  int c = qq * 128 + threadIdx.x;
#pragma unroll 1
  for (int rep = 0; rep < REP; ++rep) {
    float v = 0.f;
#pragma unroll 8
    for (int s = 0; s < SPLIT; ++s) v += partial[((size_t)s * 64 + b) * 512 + c];
    scores[b * 512 + c] = v + rb[c];
  }
}

// ---------------- K3b: exact top-128 select on scores (v1 rank logic) ---------
__global__ __launch_bounds__(512) void k_select(const float* __restrict__ scores,
                                                const float* __restrict__ cb,
                                                int* __restrict__ idx,
                                                float* __restrict__ bsel) {
  __shared__ float as_[512];
  __shared__ int keep[512];
  int b = blockIdx.x, t = threadIdx.x;
#pragma unroll 1
  for (int rep = 0; rep < REP; ++rep) {
    float v = scores[b * 512 + t];
    float av = fabsf(v);
    as_[t] = av;
    __syncthreads();
    int rank = 0;
    for (int j = 0; j < 512; ++j) {
      float aj = as_[j];
      rank += (aj > av) || (aj == av && j < t);
    }
    keep[t] = (rank < 128) ? 1 : 0;
    __syncthreads();
    if (rank < 128) {
      int pos = 0;
      for (int j = 0; j < 512; ++j) pos += (j < t) ? keep[j] : 0;
      idx[b * 128 + pos] = t;
      bsel[b * 128 + pos] = cb[t];
    }
    __syncthreads();
  }
}

// ---------------- K4: gather selected conv weights to bf16, K = tap*64+cin ----
__global__ __launch_bounds__(256) void k_gather(const float* __restrict__ cw,
                                                const int* __restrict__ idx,
                                                unsigned short* __restrict__ wsel) {
  int t = threadIdx.x, lane = t & 63, wv = t >> 6;
  int id = blockIdx.x * 4 + wv;
  int b = id >> 7, j = id & 127;
#pragma unroll 1
  for (int rep = 0; rep < REP; ++rep) {
    int c = idx[b * 128 + j];
    const float* src = cw + (size_t)c * 576 + lane * 9;
    unsigned short* dst = wsel + ((size_t)(b * 128 + j)) * 576 + lane;
#pragma unroll
    for (int i = 0; i < 9; ++i) dst[i * 64] = f2bf(src[i]);
  }
}

// ---------------- K5: selective 3x3 conv via MFMA (v1-proven body + REP) ------
__global__ __launch_bounds__(256) void k_conv(const unsigned short* __restrict__ xt,
                                              const unsigned short* __restrict__ wsel,
                                              const float* __restrict__ bsel,
                                              float* __restrict__ out) {
  __shared__ unsigned short xs[6 * 58 * XS_STRIDE];  // rows r0-1..r0+4, cols -1..56
  __shared__ unsigned short ws2[128 * WS_STRIDE];
  __shared__ float bs[128];
  int b = blockIdx.x / 25, tile = blockIdx.x % 25;
  int p0 = tile * 128;
  int r0 = p0 / 56;
  int t = threadIdx.x, lane = t & 63, wv = t >> 6;
  int l15 = lane & 15, quad = lane >> 4;
  int wy = wv >> 1, wx = wv & 1;
  const unsigned short* xb = xt + (size_t)b * HW * 64;
  const unsigned short* wrow = wsel + (size_t)b * 128 * 576;

  int pbase[4], xybase[4];
#pragma unroll
  for (int nj = 0; nj < 4; ++nj) {
    int p = p0 + wx * 64 + nj * 16 + l15;
    pbase[nj] = p;
    int pe = p > 3135 ? 3135 : p;
    int y = pe / 56, xx = pe - y * 56;
    xybase[nj] = (y - r0) * 58 + xx;
  }
  int awofs[4];
#pragma unroll
  for (int mi = 0; mi < 4; ++mi) awofs[mi] = (wy * 64 + mi * 16 + l15) * WS_STRIDE + quad * 8;

#pragma unroll 1
  for (int rep = 0; rep < REP; ++rep) {
    for (int c = t; c < 2688; c += 256) {  // 6 rows x 56 cols x 8 x 16B
      int rr = c / 448, rem = c % 448, col = rem >> 3, part = rem & 7;
      int g = r0 - 1 + rr;
      uint4 v = make_uint4(0, 0, 0, 0);
      if (g >= 0 && g < 56) v = *(const uint4*)&xb[((size_t)g * 56 + col) * 64 + part * 8];
      *(uint4*)&xs[(rr * 58 + 1 + col) * XS_STRIDE + part * 8] = v;
    }
    if (t < 96) {  // zero the col -1 / col 56 pads
      int rr = t / 16, sub = t % 16, col = (sub < 8) ? 0 : 57, part = sub & 7;
      *(uint4*)&xs[(rr * 58 + col) * XS_STRIDE + part * 8] = make_uint4(0, 0, 0, 0);
    }
    if (t < 128) bs[t] = bsel[b * 128 + t];

    floatx4 acc[4][4];
#pragma unroll
    for (int i = 0; i < 4; ++i)
#pragma unroll
      for (int j = 0; j < 4; ++j) acc[i][j] = (floatx4){0.f, 0.f, 0.f, 0.f};

#pragma unroll 1
    for (int cc = 0; cc < 18; ++cc) {
      int tap = cc >> 1, cin0 = (cc & 1) * 32;
      int dy = tap / 3, dx = tap - dy * 3;
#pragma unroll
      for (int i = 0; i < 2; ++i) {  // stage w chunk [128][32]
        int id = t + i * 256;
        int j = id >> 2, part = id & 3;
        *(uint4*)&ws2[j * WS_STRIDE + part * 8] =
            *(const uint4*)&wrow[(size_t)j * 576 + cc * 32 + part * 8];
      }
      __syncthreads();
      int sofs = (dy * 58 + dx) * XS_STRIDE + cin0 + quad * 8;
      short8 Bx[4];
#pragma unroll
      for (int nj = 0; nj < 4; ++nj) Bx[nj] = *(short8*)&xs[xybase[nj] * XS_STRIDE + sofs];
#pragma unroll
      for (int mi = 0; mi < 4; ++mi) {
        short8 Aw = *(short8*)&ws2[awofs[mi]];
#pragma unroll
        for (int nj = 0; nj < 4; ++nj)
          acc[mi][nj] = __builtin_amdgcn_mfma_f32_16x16x32_bf16(Aw, Bx[nj], acc[mi][nj], 0, 0, 0);
      }
      __syncthreads();
    }
#pragma unroll
    for (int mi = 0; mi < 4; ++mi) {
      int ch0 = wy * 64 + mi * 16 + quad * 4;
#pragma unroll
      for (int r = 0; r < 4; ++r) {
        int ch = ch0 + r;
        float bias = bs[ch];
        float* op = out + ((size_t)b * 128 + ch) * HW;
#pragma unroll
        for (int nj = 0; nj < 4; ++nj) {
          int p = pbase[nj];
          if (p < HW) op[p] = acc[mi][nj][r] + bias;
        }
      }
    }
    __syncthreads();  // rep hygiene: epilogue bs/LDS reads done before re-stage
  }
}

extern "C" void kernel_launch(void* const* d_in, const int* in_sizes, int n_in,
                              void* d_out, int out_size, void* d_ws, size_t ws_size,
                              hipStream_t stream) {
  const float* x = (const float*)d_in[0];
  const float* cw = (const float*)d_in[1];
  const float* cb = (const float*)d_in[2];
  const float* rw = (const float*)d_in[3];
  const float* rb = (const float*)d_in[4];
  float* out = (float*)d_out;
  char* ws = (char*)d_ws;
  // workspace layout — total 86,573,056 B, identical footprint to v1 (no growth).
  // scores OVERLAPS the head of wsel: k_reduce writes scores -> k_select reads
  // scores -> k_gather overwrites wsel (scores dead by then). Stream-ordered.
  unsigned short* xt = (unsigned short*)(ws);              // 25,690,112 B
  float* partial = (float*)(ws + 25690112);                // 51,380,224 B
  unsigned short* wsel = (unsigned short*)(ws + 77070336); //  9,437,184 B
  float* scores = (float*)(ws + 77070336);                 //    131,072 B (overlap)
  int* idx = (int*)(ws + 86507520);                        //     32,768 B
  float* bsel = (float*)(ws + 86540288);                   //     32,768 B

  hipLaunchKernelGGL(k_transpose, dim3(3136), dim3(256), 0, stream, x, xt);
  hipLaunchKernelGGL(k_router, dim3(2 * SPLIT), dim3(256), 0, stream, x, rw, partial);
  hipLaunchKernelGGL(k_reduce, dim3(256), dim3(128), 0, stream, partial, rb, scores);
  hipLaunchKernelGGL(k_select, dim3(64), dim3(512), 0, stream, scores, cb, idx, bsel);
  hipLaunchKernelGGL(k_gather, dim3(2048), dim3(256), 0, stream, cw, idx, wsel);
  hipLaunchKernelGGL(k_conv, dim3(1600), dim3(256), 0, stream, xt, wsel, bsel, out);
}

// Round 3
// 822.328 us; speedup vs baseline: 1.3834x; 1.3834x over previous
//
#include <hip/hip_runtime.h>

#define B_      64
#define CIN     64
#define HW      3136
#define W56     56
#define COUT    128
#define CH512   512
#define IN_DIM  200704
#define SPLIT   392          // split-K blocks; 200704/392 = 512 (FROZEN: sum order fixes selection)
#define KPER    512
#define CHUNKS  16           // KPER/32
#define XS_STRIDE 72         // padded cin stride for conv x tile

typedef __attribute__((ext_vector_type(8))) short short8;
typedef __attribute__((ext_vector_type(4))) float floatx4;

union S8U { short8 s; unsigned u[4]; };

__device__ __forceinline__ unsigned short f2bf(float f) {
  unsigned int u = __float_as_uint(f);
  u += 0x7FFFu + ((u >> 16) & 1u);
  return (unsigned short)(u >> 16);
}

// Split 8 fp32 (bit patterns in fa,fb; k-order f0..f7) into hi/lo bf16 short8.
// Bit-identical across all versions: hi = RNE(f), lo = RNE(f - bf2f(hi)).
__device__ __forceinline__ void cvt8(uint4 fa, uint4 fb, short8& H, short8& L) {
  unsigned ua[8] = {fa.x, fa.y, fa.z, fa.w, fb.x, fb.y, fb.z, fb.w};
  S8U h, l;
#pragma unroll
  for (int i = 0; i < 4; ++i) {
    unsigned u0 = ua[2 * i], u1 = ua[2 * i + 1];
    unsigned r0 = u0 + 0x7FFFu + ((u0 >> 16) & 1u);
    unsigned r1 = u1 + 0x7FFFu + ((u1 >> 16) & 1u);
    float l0 = __uint_as_float(u0) - __uint_as_float(r0 & 0xFFFF0000u);
    float l1 = __uint_as_float(u1) - __uint_as_float(r1 & 0xFFFF0000u);
    unsigned v0 = __float_as_uint(l0), v1 = __float_as_uint(l1);
    unsigned q0 = v0 + 0x7FFFu + ((v0 >> 16) & 1u);
    unsigned q1 = v1 + 0x7FFFu + ((v1 >> 16) & 1u);
    h.u[i] = (r0 >> 16) | (r1 & 0xFFFF0000u);
    l.u[i] = (q0 >> 16) | (q1 & 0xFFFF0000u);
  }
  H = h.s; L = l.s;
}

// ---------------- K1: x NCHW fp32 -> NHWC bf16 (x_t[b][pos][cin]) -------------
__global__ __launch_bounds__(256) void k_transpose(const float* __restrict__ x,
                                                   unsigned short* __restrict__ xt) {
  __shared__ float tile[64 * 65];
  int bb = blockIdx.x / 49, pt = blockIdx.x % 49;
  int p0 = pt * 64, t = threadIdx.x;
  const float* src = x + ((size_t)bb * 64) * HW + p0;
#pragma unroll
  for (int i = 0; i < 16; ++i) {
    int e = i * 256 + t, ci = e >> 6, ps = e & 63;
    tile[ci * 65 + ps] = src[(size_t)ci * HW + ps];
  }
  __syncthreads();
  unsigned short* dst = xt + ((size_t)bb * HW + p0) * 64;
#pragma unroll
  for (int i = 0; i < 16; ++i) {
    int e = i * 256 + t, ps = e >> 6, ci = e & 63;
    dst[(size_t)ps * 64 + ci] = f2bf(tile[ci * 65 + ps]);
  }
}

// ---------------- K2: router GEMM — zero LDS, zero barriers -------------------
// w has NO intra-block reuse (each (c,k) feeds exactly one wave's B fragment),
// so B fragments load STRAIGHT from global (2x dwordx4/lane), like A. No LDS,
// no __syncthreads, no vmcnt(0) lockstep: 8 free-running waves/CU + unroll-2 ILP
// keep loads continuously in flight. MFMA inputs and per-acc order bit-identical
// to the previously-passing version -> partial/scores/selection unchanged.
__global__ __launch_bounds__(256) void k_router(const float* __restrict__ x,
                                                const float* __restrict__ rw,
                                                float* __restrict__ partial) {
  int nt = blockIdx.x / SPLIT;
  int s = blockIdx.x % SPLIT;
  int kb = s * KPER;
  int t = threadIdx.x, lane = t & 63, wv = t >> 6;
  int l15 = lane & 15, quad = lane >> 4;

  floatx4 acc[4][4];
#pragma unroll
  for (int i = 0; i < 4; ++i)
#pragma unroll
    for (int j = 0; j < 4; ++j) acc[i][j] = (floatx4){0.f, 0.f, 0.f, 0.f};

  const uint4* ap[4];
  const uint4* bp[4];
#pragma unroll
  for (int mi = 0; mi < 4; ++mi)
    ap[mi] = (const uint4*)(x + (size_t)(mi * 16 + l15) * IN_DIM + kb + quad * 8);
#pragma unroll
  for (int nj = 0; nj < 4; ++nj)
    bp[nj] = (const uint4*)(rw + (size_t)(nt * 256 + wv * 64 + nj * 16 + l15) * IN_DIM +
                            kb + quad * 8);

#pragma unroll 2
  for (int cc = 0; cc < CHUNKS; ++cc) {
    // chunk cc covers k = kb + cc*32 .. +31; lane offset quad*8 baked into ap/bp.
    uint4 af[8], bf[8];
#pragma unroll
    for (int mi = 0; mi < 4; ++mi) {
      af[2 * mi]     = ap[mi][cc * 8];      // 32 floats/row per chunk = 8 uint4
      af[2 * mi + 1] = ap[mi][cc * 8 + 1];
    }
#pragma unroll
    for (int nj = 0; nj < 4; ++nj) {
      bf[2 * nj]     = bp[nj][cc * 8];
      bf[2 * nj + 1] = bp[nj][cc * 8 + 1];
    }
    short8 Ah[4], Al[4], Bh[4], Bl[4];
#pragma unroll
    for (int mi = 0; mi < 4; ++mi) cvt8(af[2 * mi], af[2 * mi + 1], Ah[mi], Al[mi]);
#pragma unroll
    for (int nj = 0; nj < 4; ++nj) cvt8(bf[2 * nj], bf[2 * nj + 1], Bh[nj], Bl[nj]);
#pragma unroll
    for (int nj = 0; nj < 4; ++nj)
#pragma unroll
      for (int mi = 0; mi < 4; ++mi) {
        acc[mi][nj] = __builtin_amdgcn_mfma_f32_16x16x32_bf16(Ah[mi], Bh[nj], acc[mi][nj], 0, 0, 0);
        acc[mi][nj] = __builtin_amdgcn_mfma_f32_16x16x32_bf16(Al[mi], Bh[nj], acc[mi][nj], 0, 0, 0);
        acc[mi][nj] = __builtin_amdgcn_mfma_f32_16x16x32_bf16(Ah[mi], Bl[nj], acc[mi][nj], 0, 0, 0);
      }
  }
#pragma unroll
  for (int mi = 0; mi < 4; ++mi)
#pragma unroll
    for (int nj = 0; nj < 4; ++nj)
#pragma unroll
      for (int r = 0; r < 4; ++r) {
        int brow = mi * 16 + quad * 4 + r;
        int cg = nt * 256 + wv * 64 + nj * 16 + l15;
        partial[((size_t)s * 64 + brow) * 512 + cg] = acc[mi][nj][r];
      }
}

// ---------------- K3a: reduce partials -> scores[64][512] ---------------------
// Sequential s order (bit-identical summation); 256 blocks for CU coverage.
__global__ __launch_bounds__(128) void k_reduce(const float* __restrict__ partial,
                                                const float* __restrict__ rb,
                                                float* __restrict__ scores) {
  int b = blockIdx.x >> 2, qq = blockIdx.x & 3;
  int c = qq * 128 + threadIdx.x;
  float v = 0.f;
#pragma unroll 8
  for (int s = 0; s < SPLIT; ++s) v += partial[((size_t)s * 64 + b) * 512 + c];
  scores[b * 512 + c] = v + rb[c];
}

// ---------------- K3b: exact top-128 select on scores -------------------------
__global__ __launch_bounds__(512) void k_select(const float* __restrict__ scores,
                                                const float* __restrict__ cb,
                                                int* __restrict__ idx,
                                                float* __restrict__ bsel) {
  __shared__ float as_[512];
  __shared__ int keep[512];
  int b = blockIdx.x, t = threadIdx.x;
  float v = scores[b * 512 + t];
  float av = fabsf(v);
  as_[t] = av;
  __syncthreads();
  int rank = 0;
  for (int j = 0; j < 512; ++j) {
    float aj = as_[j];
    rank += (aj > av) || (aj == av && j < t);
  }
  keep[t] = (rank < 128) ? 1 : 0;
  __syncthreads();
  if (rank < 128) {
    int pos = 0;
    for (int j = 0; j < 512; ++j) pos += (j < t) ? keep[j] : 0;
    idx[b * 128 + pos] = t;
    bsel[b * 128 + pos] = cb[t];
  }
}

// ---------------- K4: gather selected conv weights to bf16, K = tap*64+cin ----
__global__ __launch_bounds__(256) void k_gather(const float* __restrict__ cw,
                                                const int* __restrict__ idx,
                                                unsigned short* __restrict__ wsel) {
  int t = threadIdx.x, lane = t & 63, wv = t >> 6;
  int id = blockIdx.x * 4 + wv;
  int b = id >> 7, j = id & 127;
  int c = idx[b * 128 + j];
  const float* src = cw + (size_t)c * 576 + lane * 9;
  unsigned short* dst = wsel + ((size_t)(b * 128 + j)) * 576 + lane;
#pragma unroll
  for (int i = 0; i < 9; ++i) dst[i * 64] = f2bf(src[i]);
}

// ---------------- K5: selective 3x3 conv via MFMA -----------------------------
// v4: A=w read straight from global (only 2x intra-block reuse -> L1/L2 job, not
// LDS). Deletes ws2 staging and ALL 36 in-loop barriers; one barrier total after
// the x-halo stage. LDS 60.8 -> 50.6 KB. MFMA inputs/order bit-identical to v1.
__global__ __launch_bounds__(256) void k_conv(const unsigned short* __restrict__ xt,
                                              const unsigned short* __restrict__ wsel,
                                              const float* __restrict__ bsel,
                                              float* __restrict__ out) {
  __shared__ unsigned short xs[6 * 58 * XS_STRIDE];  // rows r0-1..r0+4, cols -1..56
  __shared__ float bs[128];
  int b = blockIdx.x / 25, tile = blockIdx.x % 25;
  int p0 = tile * 128;
  int r0 = p0 / 56;
  int t = threadIdx.x, lane = t & 63, wv = t >> 6;
  int l15 = lane & 15, quad = lane >> 4;
  int wy = wv >> 1, wx = wv & 1;
  const unsigned short* xb = xt + (size_t)b * HW * 64;
  const unsigned short* wrow = wsel + (size_t)b * 128 * 576;

  for (int c = t; c < 2688; c += 256) {  // 6 rows x 56 cols x 8 x 16B
    int rr = c / 448, rem = c % 448, col = rem >> 3, part = rem & 7;
    int g = r0 - 1 + rr;
    uint4 v = make_uint4(0, 0, 0, 0);
    if (g >= 0 && g < 56) v = *(const uint4*)&xb[((size_t)g * 56 + col) * 64 + part * 8];
    *(uint4*)&xs[(rr * 58 + 1 + col) * XS_STRIDE + part * 8] = v;
  }
  if (t < 96) {  // zero the col -1 / col 56 pads
    int rr = t / 16, sub = t % 16, col = (sub < 8) ? 0 : 57, part = sub & 7;
    *(uint4*)&xs[(rr * 58 + col) * XS_STRIDE + part * 8] = make_uint4(0, 0, 0, 0);
  }
  if (t < 128) bs[t] = bsel[b * 128 + t];

  int pbase[4], xybase[4];
#pragma unroll
  for (int nj = 0; nj < 4; ++nj) {
    int p = p0 + wx * 64 + nj * 16 + l15;
    pbase[nj] = p;
    int pe = p > 3135 ? 3135 : p;
    int y = pe / 56, xx = pe - y * 56;
    xybase[nj] = (y - r0) * 58 + xx;
  }
  const short8* awp[4];
#pragma unroll
  for (int mi = 0; mi < 4; ++mi)
    awp[mi] = (const short8*)(wrow + (size_t)(wy * 64 + mi * 16 + l15) * 576 + quad * 8);

  floatx4 acc[4][4];
#pragma unroll
  for (int i = 0; i < 4; ++i)
#pragma unroll
    for (int j = 0; j < 4; ++j) acc[i][j] = (floatx4){0.f, 0.f, 0.f, 0.f};
  __syncthreads();

#pragma unroll 2
  for (int cc = 0; cc < 18; ++cc) {
    int tap = cc >> 1, cin0 = (cc & 1) * 32;
    int dy = tap / 3, dx = tap - dy * 3;
    short8 Aw[4];
#pragma unroll
    for (int mi = 0; mi < 4; ++mi) Aw[mi] = awp[mi][cc * 4];  // k-offset cc*32 shorts
    int sofs = (dy * 58 + dx) * XS_STRIDE + cin0 + quad * 8;
    short8 Bx[4];
#pragma unroll
    for (int nj = 0; nj < 4; ++nj) Bx[nj] = *(short8*)&xs[xybase[nj] * XS_STRIDE + sofs];
#pragma unroll
    for (int mi = 0; mi < 4; ++mi)
#pragma unroll
      for (int nj = 0; nj < 4; ++nj)
        acc[mi][nj] = __builtin_amdgcn_mfma_f32_16x16x32_bf16(Aw[mi], Bx[nj], acc[mi][nj], 0, 0, 0);
  }
#pragma unroll
  for (int mi = 0; mi < 4; ++mi) {
    int ch0 = wy * 64 + mi * 16 + quad * 4;
#pragma unroll
    for (int r = 0; r < 4; ++r) {
      int ch = ch0 + r;
      float bias = bs[ch];
      float* op = out + ((size_t)b * 128 + ch) * HW;
#pragma unroll
      for (int nj = 0; nj < 4; ++nj) {
        int p = pbase[nj];
        if (p < HW) op[p] = acc[mi][nj][r] + bias;
      }
    }
  }
}

extern "C" void kernel_launch(void* const* d_in, const int* in_sizes, int n_in,
                              void* d_out, int out_size, void* d_ws, size_t ws_size,
                              hipStream_t stream) {
  const float* x = (const float*)d_in[0];
  const float* cw = (const float*)d_in[1];
  const float* cb = (const float*)d_in[2];
  const float* rw = (const float*)d_in[3];
  const float* rb = (const float*)d_in[4];
  float* out = (float*)d_out;
  char* ws = (char*)d_ws;
  // workspace layout — total 86,573,056 B (v1 footprint; proven). scores overlaps
  // the head of wsel: k_reduce writes scores -> k_select reads -> k_gather then
  // overwrites wsel (scores dead by then). Stream-ordered, safe.
  unsigned short* xt = (unsigned short*)(ws);              // 25,690,112 B
  float* partial = (float*)(ws + 25690112);                // 51,380,224 B
  unsigned short* wsel = (unsigned short*)(ws + 77070336); //  9,437,184 B
  float* scores = (float*)(ws + 77070336);                 //    131,072 B (overlap)
  int* idx = (int*)(ws + 86507520);                        //     32,768 B
  float* bsel = (float*)(ws + 86540288);                   //     32,768 B

  hipLaunchKernelGGL(k_transpose, dim3(3136), dim3(256), 0, stream, x, xt);
  hipLaunchKernelGGL(k_router, dim3(2 * SPLIT), dim3(256), 0, stream, x, rw, partial);
  hipLaunchKernelGGL(k_reduce, dim3(256), dim3(128), 0, stream, partial, rb, scores);
  hipLaunchKernelGGL(k_select, dim3(64), dim3(512), 0, stream, scores, cb, idx, bsel);
  hipLaunchKernelGGL(k_gather, dim3(2048), dim3(256), 0, stream, cw, idx, wsel);
  hipLaunchKernelGGL(k_conv, dim3(1600), dim3(256), 0, stream, xt, wsel, bsel, out);
}